// Round 8
// baseline (76.160 us; speedup 1.0000x reference)
//
#include <hip/hip_runtime.h>
#include <hip/hip_bf16.h>
#include <cmath>

#define B_    4
#define C_    128
#define O_    128
#define K2T   9
#define CK    1152            // C_*K2T
#define NPIX  4096            // 64*64
#define CHSL  512             // per-channel slab: 8 rows * 64 cols (floats)
#define SLABSZ (32 * CHSL)    // 16384 floats = 64 KB per buffer

using bf16   = __bf16;
using bf16x8 = __attribute__((ext_vector_type(8))) __bf16;
using f32x4  = __attribute__((ext_vector_type(4))) float;

// ws layout (bytes):
//   [0, 294912)        w_bf   bf16[128*1152]  K-reordered: [o][cc*288 + k*32 + cq]
//   [294912, 368640)   wom_bf bf16[32*1152]   same K order, rows 27..31 zero
#define WS_WBF 0
#define WS_WOM 294912

// ---------------- kernel R: repack weights (K-reordered) ----------------
__global__ void __launch_bounds__(256) repack_kernel(
    const float* __restrict__ org_w, const float* __restrict__ offset_w,
    const float* __restrict__ mask_w, bf16* __restrict__ w_bf,
    bf16* __restrict__ wom_bf) {
  int t = blockIdx.x * 256 + threadIdx.x;   // 0 .. 160*1152-1
  if (t >= 160 * CK) return;
  int row = t / CK, r = t % CK;
  int cc = r / 288, rr = r % 288;
  int k = rr >> 5, cq = rr & 31;
  int c = cc * 32 + cq;
  if (row < 128) {
    w_bf[t] = (bf16)org_w[((size_t)row * C_ + c) * K2T + k];
  } else {
    int ch = row - 128;
    float v = 0.f;
    if (ch < 18)      v = offset_w[((size_t)ch * C_ + c) * K2T + k];
    else if (ch < 27) v = mask_w[((size_t)(ch - 18) * C_ + c) * K2T + k];
    wom_bf[(size_t)ch * CK + r] = (bf16)v;
  }
}

__device__ __forceinline__ void gl_lds16(const float* src, float* lds_uniform) {
  __builtin_amdgcn_global_load_lds(
      (const __attribute__((address_space(1))) void*)src,
      (__attribute__((address_space(3))) void*)lds_uniform, 16, 0, 0);
}

// ---- fused kernel: direct-register B-fragments, no valbuf ----
// 256 threads = 4 waves; wave w owns pixels w*16..w*16+15, all M=128.
__global__ void __launch_bounds__(256) deform_fused_kernel(
    const float* __restrict__ x, const bf16* __restrict__ w_bf,
    const bf16* __restrict__ wom_bf, const float* __restrict__ off_b,
    const float* __restrict__ mask_b, float* __restrict__ out) {
  __shared__ __align__(16) float xslab[2 * SLABSZ + 64];  // 131,328 B (+guard row)
  __shared__ __align__(16) float S_lds[32 * 64];          // 8,192 B

  int tid  = threadIdx.x;
  int w    = tid >> 6, lane = tid & 63;
  int bid0 = blockIdx.x;
  int bid  = (bid0 & 7) * 32 + (bid0 >> 3);  // XCD swizzle (bijective 256=8*32)
  int b    = bid >> 6, ho = bid & 63;

  const float* xb = x + (size_t)b * C_ * NPIX;
  int y_start = ho - 3; y_start = y_start < 0 ? 0 : (y_start > 56 ? 56 : y_start);
  int l15 = lane & 15, l4 = lane >> 4;
  int mypx  = w * 16 + l15;      // this lane's output pixel (column)
  int sigma = l4 * 8;            // read-side col XOR (dwords) — lane-constant
  int cq0   = l4 * 8;            // this lane's 8-channel group within a cc-chunk

  // stage one cc-chunk (32 channels x 8 rows x 64 cols) into buffer bufw.
  // LDS linear; global source col-chunk pre-XOR-swizzled by ((ch>>3)&3)*2.
  auto stage = [&](int ccw, int bufw) {
    float* dstb = xslab + bufw * SLABSZ;
#pragma unroll
    for (int i = 0; i < 16; ++i) {
      int ch = w * 8 + (i >> 1), part = i & 1;
      int s4c = ((ch >> 3) & 3) * 2;           // 16B-chunk XOR
      const float* src = xb + (size_t)(ccw * 32 + ch) * NPIX
                       + (y_start + part * 4 + l4) * 64 + ((l15 ^ s4c) << 2);
      gl_lds16(src, dstb + ch * CHSL + part * 256);
    }
  };

  // ---- phase-1 zero-offset per-tap params ----
  float f1k[9]; int a1k[9];
#pragma unroll
  for (int k = 0; k < 9; ++k) {
    int ki = k / 3, kj = k % 3;
    int row = ho - 1 + ki, colu = mypx - 1 + kj;
    bool ok = ((unsigned)row < 64u) && ((unsigned)colu < 64u);
    int rc  = row  < 0 ? 0 : (row  > 63 ? 63 : row);
    int ccl = colu < 0 ? 0 : (colu > 63 ? 63 : colu);
    f1k[k] = ok ? 1.f : 0.f;
    a1k[k] = (rc - y_start) * 64 + (ccl ^ sigma);
  }

  stage(0, 0);  // prologue

  // ================= PHASE 1: offset/mask conv (M=32) =================
  f32x4 acc1[2] = {};
  {
    const bf16* wmb = wom_bf + (size_t)l15 * CK + cq0;
#pragma unroll 1
    for (int cc = 0; cc < 4; ++cc) {
      asm volatile("s_waitcnt vmcnt(0)" ::: "memory");  // my stage landed
      __builtin_amdgcn_s_barrier();                     // everyone's landed
      __builtin_amdgcn_sched_barrier(0);
      stage((cc + 1) & 3, (cc + 1) & 1);                // cc=3 pre-stages phase-2 cc0
      const float* sb0 = xslab + (cc & 1) * SLABSZ;
#pragma unroll
      for (int ks = 0; ks < 9; ++ks) {
        bf16x8 bfrag;
#pragma unroll
        for (int j = 0; j < 8; ++j)
          bfrag[j] = (bf16)(f1k[ks] * sb0[(cq0 + j) * CHSL + a1k[ks]]);
        bf16x8 a0 = *(const bf16x8*)(wmb + cc * 288 + ks * 32);
        bf16x8 a1 = *(const bf16x8*)(wmb + (size_t)16 * CK + cc * 288 + ks * 32);
        acc1[0] = __builtin_amdgcn_mfma_f32_16x16x32_bf16(a0, bfrag, acc1[0], 0, 0, 0);
        acc1[1] = __builtin_amdgcn_mfma_f32_16x16x32_bf16(a1, bfrag, acc1[1], 0, 0, 0);
      }
    }
  }
  // S write: rows = offmask channel 0..31, cols = pixel
#pragma unroll
  for (int mi = 0; mi < 2; ++mi)
#pragma unroll
    for (int r = 0; r < 4; ++r)
      S_lds[(mi * 16 + l4 * 4 + r) * 64 + mypx] = acc1[mi][r];
  __syncthreads();

  // ---- sampling params for my pixel, all 9 taps (exact corner clamps) ----
  float pw_[9][4]; int psa[9], psb[9], pdy[9];
#pragma unroll
  for (int k = 0; k < 9; ++k) {
    float dy = S_lds[(2 * k) * 64 + mypx]     + off_b[2 * k];
    float dx = S_lds[(2 * k + 1) * 64 + mypx] + off_b[2 * k + 1];
    float mz = S_lds[(18 + k) * 64 + mypx]    + mask_b[k];
    float m  = 1.f / (1.f + expf(-mz));
    int ki = k / 3, kj = k % 3;
    float py = (float)(ho   - 1 + ki) + dy;
    float px = (float)(mypx - 1 + kj) + dx;
    float fy = floorf(py), fx = floorf(px);
    int y0 = (int)fy, x0 = (int)fx;
    float wy = py - fy, wx = px - fx;
    float vy0 = ((unsigned)y0       < 64u) ? 1.f : 0.f;
    float vy1 = ((unsigned)(y0 + 1) < 64u) ? 1.f : 0.f;
    float vx0 = ((unsigned)x0       < 64u) ? 1.f : 0.f;
    float vx1 = ((unsigned)(x0 + 1) < 64u) ? 1.f : 0.f;
    int y0c = y0 < 0 ? 0 : (y0 > 63 ? 63 : y0);
    int y1c = y0 + 1 < 0 ? 0 : (y0 + 1 > 63 ? 63 : y0 + 1);
    int c0c = x0 < 0 ? 0 : (x0 > 63 ? 63 : x0);
    int c1c = x0 + 1 < 0 ? 0 : (x0 + 1 > 63 ? 63 : x0 + 1);
    pw_[k][0] = (1.f - wy) * (1.f - wx) * m * vy0 * vx0;
    pw_[k][1] = (1.f - wy) * wx         * m * vy0 * vx1;
    pw_[k][2] = wy * (1.f - wx)         * m * vy1 * vx0;
    pw_[k][3] = wy * wx                 * m * vy1 * vx1;
    int rr0 = y0c - y_start; rr0 = rr0 < 0 ? 0 : (rr0 > 7 ? 7 : rr0);
    psa[k] = rr0 * 64 + (c0c ^ sigma);
    psb[k] = rr0 * 64 + (c1c ^ sigma);
    pdy[k] = y1c - y0c;   // 0 or 1: row select for the v10/v11 corners
  }

  // ================= PHASE 2: deformable conv (M=128) =================
  f32x4 acc[8] = {};
  {
    const bf16* wab = w_bf + (size_t)l15 * CK + cq0;
#pragma unroll 1
    for (int cc = 0; cc < 4; ++cc) {
      asm volatile("s_waitcnt vmcnt(0)" ::: "memory");
      __builtin_amdgcn_s_barrier();
      __builtin_amdgcn_sched_barrier(0);
      if (cc < 3) stage(cc + 1, (cc + 1) & 1);
      const float* sb0 = xslab + (cc & 1) * SLABSZ;
#pragma unroll
      for (int ks = 0; ks < 9; ++ks) {
        bf16x8 bfrag;
#pragma unroll
        for (int j = 0; j < 8; ++j) {
          const float* sbp = sb0 + (cq0 + j) * CHSL;
          float a0v = sbp[psa[ks]], a1v = sbp[psa[ks] + 64];   // ds_read2
          float b0v = sbp[psb[ks]], b1v = sbp[psb[ks] + 64];   // ds_read2
          float v10 = pdy[ks] ? a1v : a0v;
          float v11 = pdy[ks] ? b1v : b0v;
          bfrag[j] = (bf16)(pw_[ks][0] * a0v + pw_[ks][1] * b0v +
                            pw_[ks][2] * v10 + pw_[ks][3] * v11);
        }
#pragma unroll
        for (int m = 0; m < 8; ++m) {
          bf16x8 af = *(const bf16x8*)(wab + (size_t)m * 16 * CK + cc * 288 + ks * 32);
          acc[m] = __builtin_amdgcn_mfma_f32_16x16x32_bf16(af, bfrag, acc[m], 0, 0, 0);
        }
      }
    }
  }

  // ---- epilogue: D row=(l4*4+r)+m*16 (=o), col=l15 (=mypx) ----
  float* ob = out + (size_t)b * O_ * NPIX + ho * 64 + mypx;
#pragma unroll
  for (int m = 0; m < 8; ++m)
#pragma unroll
    for (int r = 0; r < 4; ++r)
      ob[(size_t)(m * 16 + l4 * 4 + r) * NPIX] = acc[m][r];
}

// ---------------- launch ----------------
extern "C" void kernel_launch(void* const* d_in, const int* in_sizes, int n_in,
                              void* d_out, int out_size, void* d_ws, size_t ws_size,
                              hipStream_t stream) {
  const float* x        = (const float*)d_in[0];
  const float* org_w    = (const float*)d_in[1];
  const float* offset_w = (const float*)d_in[2];
  const float* off_b    = (const float*)d_in[3];
  const float* mask_w   = (const float*)d_in[4];
  const float* mask_b   = (const float*)d_in[5];
  float* out = (float*)d_out;
  char*  ws  = (char*)d_ws;

  bf16* w_bf   = (bf16*)(ws + WS_WBF);
  bf16* wom_bf = (bf16*)(ws + WS_WOM);

  repack_kernel<<<720, 256, 0, stream>>>(org_w, offset_w, mask_w, w_bf, wom_bf);
  deform_fused_kernel<<<256, 256, 0, stream>>>(x, w_bf, wom_bf, off_b, mask_b, out);
}

// Round 9
// 51.120 us; speedup vs baseline: 1.4898x; 1.4898x over previous
//
#include <hip/hip_runtime.h>
#include <hip/hip_bf16.h>
#include <cmath>

#define B_    4
#define C_    128
#define O_    128
#define K2T   9
#define CK    1152          // C_*K2T
#define NPIX  4096          // 64*64
#define VPITCH 296          // valbuf row pitch in bf16 (592B = 37*16B)
#define ROWS  12            // slab rows: ho-5 .. ho+6  (|dy|<=4 safe, ~11 sigma)
#define BUFF  6144          // one slab buffer: 8 ch * 12 rows * 64 cols floats

using bf16   = __bf16;
using bf16x4 = __attribute__((ext_vector_type(4))) __bf16;
using bf16x8 = __attribute__((ext_vector_type(8))) __bf16;
using f32x4  = __attribute__((ext_vector_type(4))) float;

// ws layout (bytes):
//   [0, 294912)        w_bf   bf16[128*1152]  K-reordered: [o][cc*288 + k*32 + cq]
//   [294912, 368640)   wom_bf bf16[32*1152]   same K order, rows 27..31 zero
#define WS_WBF 0
#define WS_WOM 294912

// ---------------- kernel R: repack weights (K-reordered) ----------------
__global__ void __launch_bounds__(256) repack_kernel(
    const float* __restrict__ org_w, const float* __restrict__ offset_w,
    const float* __restrict__ mask_w, bf16* __restrict__ w_bf,
    bf16* __restrict__ wom_bf) {
  int t = blockIdx.x * 256 + threadIdx.x;   // 0 .. 160*1152-1
  if (t >= 160 * CK) return;
  int row = t / CK, r = t % CK;
  int cc = r / 288, rr = r % 288;
  int k = rr >> 5, cq = rr & 31;
  int c = cc * 32 + cq;
  if (row < 128) {
    w_bf[t] = (bf16)org_w[((size_t)row * C_ + c) * K2T + k];
  } else {
    int ch = row - 128;
    float v = 0.f;
    if (ch < 18)      v = offset_w[((size_t)ch * C_ + c) * K2T + k];
    else if (ch < 27) v = mask_w[((size_t)(ch - 18) * C_ + c) * K2T + k];
    wom_bf[(size_t)ch * CK + r] = (bf16)v;
  }
}

__device__ __forceinline__ void gl_lds16(const float* src, float* lds_uniform) {
  __builtin_amdgcn_global_load_lds(
      (const __attribute__((address_space(1))) void*)src,
      (__attribute__((address_space(3))) void*)lds_uniform, 16, 0, 0);
}

// ---------------- fused kernel: R4 base + counted-vmcnt pipeline ------------
__global__ void __launch_bounds__(576) deform_fused_kernel(
    const float* __restrict__ x, const bf16* __restrict__ w_bf,
    const bf16* __restrict__ wom_bf, const float* __restrict__ off_b,
    const float* __restrict__ mask_b, float* __restrict__ out) {
  __shared__ __align__(16) float xslab[3 * BUFF];        // 73,728 B (3 bufs)
  __shared__ __align__(16) bf16  valbuf[64 * VPITCH];    // 37,888 B
  __shared__ __align__(16) float S_lds[32 * 64];         // 8,192 B

  int tid  = threadIdx.x;
  int bid0 = blockIdx.x;
  int bid  = (bid0 & 7) * 32 + (bid0 >> 3);  // XCD swizzle (bijective 256=8*32)
  int b    = bid >> 6, ho = bid & 63;
  int lane = tid & 63, wv = tid >> 6;        // 9 waves
  int l15  = lane & 15, l4 = lane >> 4;
  bool w8  = (wv < 8);

  const float* xb = x + (size_t)b * C_ * NPIX;
  float* xs3 = xslab;                        // phase-1 alias: [32 ch][3*64]

  // ================= PHASE 1: offset/mask conv (R4-proven, verbatim) =======
  f32x4 acc1 = {};
  {
    int mf  = wv & 1, nfq = wv >> 1;
    const bf16* wbase1 = wom_bf + (size_t)(mf * 16 + l15) * CK + l4 * 8;
    const bf16* vbase1 = valbuf + (size_t)(nfq * 16 + l15) * VPITCH + l4 * 8;
    int p  = lane;
    int g2 = wv;           // 0..8 (8 skips build)
    for (int cc = 0; cc < 4; ++cc) {
      __syncthreads();
#pragma unroll
      for (int i = 0; i < 3; ++i) {
        int slot = tid + i * 576;
        if (slot < 1536) {
          int ch = slot / 48, rem2 = slot % 48;
          int row = rem2 / 16, c16 = rem2 & 15;
          int y = ho - 1 + row;
          float4 v = make_float4(0.f, 0.f, 0.f, 0.f);
          if ((unsigned)y < 64u)
            v = *((const float4*)(xb + (size_t)(cc * 32 + ch) * NPIX + y * 64) + c16);
          *(float4*)(&xs3[ch * 192 + row * 64 + c16 * 4]) = v;
        }
      }
      __syncthreads();
      if (g2 < 8) {
#pragma unroll
        for (int k = 0; k < 9; ++k) {
          int ki = k / 3, kj = k % 3;
          int px = p - 1 + kj;
          bf16x4 pr;
#pragma unroll
          for (int cqi = 0; cqi < 4; ++cqi) {
            int cq = (g2 << 2) + cqi;
            float v = ((unsigned)px < 64u) ? xs3[cq * 192 + ki * 64 + px] : 0.f;
            pr[cqi] = (bf16)v;
          }
          *(bf16x4*)(valbuf + (size_t)p * VPITCH + k * 32 + (g2 << 2)) = pr;
        }
      }
      __syncthreads();
      if (w8) {
        __builtin_amdgcn_s_setprio(1);
#pragma unroll
        for (int ks = 0; ks < 9; ++ks) {
          bf16x8 a  = *(const bf16x8*)(wbase1 + cc * 288 + ks * 32);
          bf16x8 bv = *(const bf16x8*)(vbase1 + ks * 32);
          acc1 = __builtin_amdgcn_mfma_f32_16x16x32_bf16(a, bv, acc1, 0, 0, 0);
        }
        __builtin_amdgcn_s_setprio(0);
      }
    }
  }
  __syncthreads();
  if (w8) {
    int mf = wv & 1, nfq = wv >> 1;
    int so = mf * 16 + l4 * 4;
    int sp = nfq * 16 + l15;
#pragma unroll
    for (int r = 0; r < 4; ++r) S_lds[(so + r) * 64 + sp] = acc1[r];
  }
  __syncthreads();

  // ---- staging helper: wave w stages channel (cc*32 + g*8 + w), 12 rows ----
  auto stage = [&](int it2) {
    if (w8 && it2 < 16) {
      int ch = (it2 >> 2) * 32 + (it2 & 3) * 8 + wv;
      float* dst = xslab + (it2 % 3) * BUFF + wv * 768;
      const float* srcb = xb + (size_t)ch * NPIX + l15 * 4;
#pragma unroll
      for (int j = 0; j < 3; ++j) {
        int y = ho - 5 + j * 4 + l4; y = y < 0 ? 0 : (y > 63 ? 63 : y);
        gl_lds16(srcb + y * 64, dst + j * 256);
      }
    }
  };

  // prologue: stage it=0 and it=1 (buf0, buf1); params compute overlaps
  stage(0);
  stage(1);
  __builtin_amdgcn_sched_barrier(0);

  // ---- sampling params: entry (k=wv, p=lane), one per thread ----
  float pw0, pw1, pw2, pw3;
  int   psa, psb, vbo;
  {
    int k = wv, p = lane;
    float dy = S_lds[(2 * k) * 64 + p]     + off_b[2 * k];
    float dx = S_lds[(2 * k + 1) * 64 + p] + off_b[2 * k + 1];
    float mz = S_lds[(18 + k) * 64 + p]    + mask_b[k];
    float m  = 1.f / (1.f + expf(-mz));
    int ki = k / 3, kj = k % 3;
    float py = (float)(ho - 1 + ki) + dy;
    float px = (float)(p  - 1 + kj) + dx;
    float fy = floorf(py), fx = floorf(px);
    int y0 = (int)fy, x0 = (int)fx;
    float wy = py - fy, wx = px - fx;
    float vy0 = ((unsigned)y0       < 64u) ? 1.f : 0.f;
    float vy1 = ((unsigned)(y0 + 1) < 64u) ? 1.f : 0.f;
    float vx0 = ((unsigned)x0       < 64u) ? 1.f : 0.f;
    float vx1 = ((unsigned)(x0 + 1) < 64u) ? 1.f : 0.f;
    int r0  = y0 - (ho - 5);
    int ir0 = r0 < 0 ? 0 : (r0 > ROWS - 2 ? ROWS - 2 : r0);  // ir1 = ir0+1
    int c0  = x0 < 0 ? 0 : (x0 > 63 ? 63 : x0);
    int x1  = x0 + 1;
    int c1  = x1 < 0 ? 0 : (x1 > 63 ? 63 : x1);
    pw0 = (1.f - wy) * (1.f - wx) * m * vy0 * vx0;
    pw1 = (1.f - wy) * wx         * m * vy0 * vx1;
    pw2 = wy * (1.f - wx)         * m * vy1 * vx0;
    pw3 = wy * wx                 * m * vy1 * vx1;
    psa = ir0 * 64 + c0;      // corners (y0,x0)/(y0+1,x0) at +0,+64
    psb = ir0 * 64 + c1;      // corners (y0,x1)/(y0+1,x1) at +0,+64
    vbo = p * VPITCH + k * 32;
  }

  // ================= PHASE 2: counted-vmcnt pipelined loop =================
  f32x4 acc[4] = {};
  bf16x8 aF[9] = {};
  const bf16* wbase = w_bf + (size_t)(wv * 16 + l15) * CK + l4 * 8;
  const bf16* vbase = valbuf + (size_t)l15 * VPITCH + l4 * 8;

#pragma unroll 1
  for (int it = 0; it < 16; ++it) {
    int g = it & 3, cc = it >> 2;
    // counted wait: retire batch(it) (+A(cc) by g2); keep younger batches flying
    if (it == 15)      asm volatile("s_waitcnt vmcnt(0)" ::: "memory");
    else if (g == 1)   asm volatile("s_waitcnt vmcnt(12)" ::: "memory");
    else               asm volatile("s_waitcnt vmcnt(3)" ::: "memory");
    __builtin_amdgcn_s_barrier();           // all waves' batch(it) landed
    __builtin_amdgcn_sched_barrier(0);
    if (g == 0 && w8) {                     // A-frags for this cc -> registers
#pragma unroll
      for (int ks = 0; ks < 9; ++ks)
        aF[ks] = *(const bf16x8*)(wbase + cc * 288 + ks * 32);
      __builtin_amdgcn_sched_barrier(0);
    }
    stage(it + 2);                          // issue next-next batch
    __builtin_amdgcn_sched_barrier(0);
    {   // sample 8 slab channels at my (k,p): one bf16x8 valbuf write
      const float* sbuf = xslab + (it % 3) * BUFF;
      bf16x8 pack;
#pragma unroll
      for (int s = 0; s < 8; ++s) {
        const float* cb = sbuf + s * 768;
        float a0 = cb[psa], a1 = cb[psa + 64];   // ds_read2
        float b0 = cb[psb], b1 = cb[psb + 64];   // ds_read2
        pack[s] = (bf16)(pw0 * a0 + pw1 * b0 + pw2 * a1 + pw3 * b1);
      }
      *(bf16x8*)(valbuf + vbo + g * 8) = pack;
    }
    if (g == 3) {
      asm volatile("s_waitcnt lgkmcnt(0)" ::: "memory");  // my valbuf writes out
      __builtin_amdgcn_s_barrier();                       // everyone's out
      __builtin_amdgcn_sched_barrier(0);
      if (w8) {
        __builtin_amdgcn_s_setprio(1);
#pragma unroll
        for (int ks = 0; ks < 9; ++ks) {
#pragma unroll
          for (int nf = 0; nf < 4; ++nf) {
            bf16x8 bv = *(const bf16x8*)(vbase + (size_t)nf * 16 * VPITCH + ks * 32);
            acc[nf] = __builtin_amdgcn_mfma_f32_16x16x32_bf16(aF[ks], bv, acc[nf], 0, 0, 0);
          }
        }
        __builtin_amdgcn_s_setprio(0);
      }
    }
  }

  // ---- epilogue: D row=(l4*4+r) (=o within wave), col=l15 (=px) ----
  if (w8) {
    float* ob = out + (size_t)b * O_ * NPIX + ho * 64;
#pragma unroll
    for (int nf = 0; nf < 4; ++nf)
#pragma unroll
      for (int r = 0; r < 4; ++r) {
        int o = wv * 16 + l4 * 4 + r;
        int p = nf * 16 + l15;
        ob[(size_t)o * NPIX + p] = acc[nf][r];
      }
  }
}

// ---------------- launch ----------------
extern "C" void kernel_launch(void* const* d_in, const int* in_sizes, int n_in,
                              void* d_out, int out_size, void* d_ws, size_t ws_size,
                              hipStream_t stream) {
  const float* x        = (const float*)d_in[0];
  const float* org_w    = (const float*)d_in[1];
  const float* offset_w = (const float*)d_in[2];
  const float* off_b    = (const float*)d_in[3];
  const float* mask_w   = (const float*)d_in[4];
  const float* mask_b   = (const float*)d_in[5];
  float* out = (float*)d_out;
  char*  ws  = (char*)d_ws;

  bf16* w_bf   = (bf16*)(ws + WS_WBF);
  bf16* wom_bf = (bf16*)(ws + WS_WOM);

  repack_kernel<<<720, 256, 0, stream>>>(org_w, offset_w, mask_w, w_bf, wom_bf);
  deform_fused_kernel<<<256, 576, 0, stream>>>(x, w_bf, wom_bf, off_b, mask_b, out);
}

// Round 10
// 47.481 us; speedup vs baseline: 1.6040x; 1.0766x over previous
//
#include <hip/hip_runtime.h>
#include <hip/hip_bf16.h>
#include <cmath>

#define B_    4
#define C_    128
#define O_    128
#define K2T   9
#define CK    1152          // C_*K2T
#define NPIX  4096          // 64*64
#define ROWS  8             // slab rows: ho-3 .. ho+4 (R8-validated window)
#define BUFC  512           // floats per channel slab (8 rows * 64)
#define BUFF  8192          // floats per buffer (16 ch * 512) = 32 KB
#define NGRP  36            // valbuf groups (kk>>3)

using bf16   = __bf16;
using bf16x4 = __attribute__((ext_vector_type(4))) __bf16;
using bf16x8 = __attribute__((ext_vector_type(8))) __bf16;
using f32x4  = __attribute__((ext_vector_type(4))) float;

// ws layout (bytes):
//   [0, 294912)        w_bf   bf16[128*1152]  K-reordered: [o][cc*288 + k*32 + cq]
//   [294912, 368640)   wom_bf bf16[32*1152]   same K order, rows 27..31 zero
#define WS_WBF 0
#define WS_WOM 294912

// ---------------- kernel R: repack weights (K-reordered) ----------------
__global__ void __launch_bounds__(256) repack_kernel(
    const float* __restrict__ org_w, const float* __restrict__ offset_w,
    const float* __restrict__ mask_w, bf16* __restrict__ w_bf,
    bf16* __restrict__ wom_bf) {
  int t = blockIdx.x * 256 + threadIdx.x;   // 0 .. 160*1152-1
  if (t >= 160 * CK) return;
  int row = t / CK, r = t % CK;
  int cc = r / 288, rr = r % 288;
  int k = rr >> 5, cq = rr & 31;
  int c = cc * 32 + cq;
  if (row < 128) {
    w_bf[t] = (bf16)org_w[((size_t)row * C_ + c) * K2T + k];
  } else {
    int ch = row - 128;
    float v = 0.f;
    if (ch < 18)      v = offset_w[((size_t)ch * C_ + c) * K2T + k];
    else if (ch < 27) v = mask_w[((size_t)(ch - 18) * C_ + c) * K2T + k];
    wom_bf[(size_t)ch * CK + r] = (bf16)v;
  }
}

__device__ __forceinline__ void gl_lds16(const float* src, float* lds_uniform) {
  __builtin_amdgcn_global_load_lds(
      (const __attribute__((address_space(1))) void*)src,
      (__attribute__((address_space(3))) void*)lds_uniform, 16, 0, 0);
}

// ------------- fused kernel: 8 fat phases, v36 valbuf, vmcnt(4) -------------
__global__ void __launch_bounds__(576) deform_fused_kernel(
    const float* __restrict__ x, const bf16* __restrict__ w_bf,
    const bf16* __restrict__ wom_bf, const float* __restrict__ off_b,
    const float* __restrict__ mask_b, float* __restrict__ out) {
  __shared__ __align__(16) float xslab[3 * BUFF];        // 98,304 B (3 bufs)
  __shared__ __align__(16) bf16  valbuf[NGRP * 512];     // 36,864 B
  __shared__ __align__(16) float S_lds[32 * 64];         // 8,192 B

  int tid  = threadIdx.x;
  int bid0 = blockIdx.x;
  int bid  = (bid0 & 7) * 32 + (bid0 >> 3);  // XCD swizzle (bijective 256=8*32)
  int b    = bid >> 6, ho = bid & 63;
  int lane = tid & 63, wv = tid >> 6;        // 9 waves
  int l15  = lane & 15, l4 = lane >> 4;
  bool w8  = (wv < 8);

  const float* xb = x + (size_t)b * C_ * NPIX;
  float* xs3 = xslab;                        // phase-1 alias: [32 ch][3*64]

  // ================= PHASE 1: offset/mask conv (R4-proven; v36 addressing) ==
  f32x4 acc1 = {};
  {
    int mf  = wv & 1, nfq = wv >> 1;
    const bf16* wbase1 = wom_bf + (size_t)(mf * 16 + l15) * CK + l4 * 8;
    const bf16* vb1    = valbuf + l4 * 512 + (nfq * 16 + l15) * 8;
    int p  = lane;
    int g2 = wv;           // 0..8 (8 skips build)
    for (int cc = 0; cc < 4; ++cc) {
      __syncthreads();
#pragma unroll
      for (int i = 0; i < 3; ++i) {
        int slot = tid + i * 576;
        if (slot < 1536) {
          int ch = slot / 48, rem2 = slot % 48;
          int row = rem2 / 16, c16 = rem2 & 15;
          int y = ho - 1 + row;
          float4 v = make_float4(0.f, 0.f, 0.f, 0.f);
          if ((unsigned)y < 64u)
            v = *((const float4*)(xb + (size_t)(cc * 32 + ch) * NPIX + y * 64) + c16);
          *(float4*)(&xs3[ch * 192 + row * 64 + c16 * 4]) = v;
        }
      }
      __syncthreads();
      if (g2 < 8) {
#pragma unroll
        for (int k = 0; k < 9; ++k) {
          int ki = k / 3, kj = k % 3;
          int px = p - 1 + kj;
          bf16x4 pr;
#pragma unroll
          for (int cqi = 0; cqi < 4; ++cqi) {
            int cq = (g2 << 2) + cqi;
            float v = ((unsigned)px < 64u) ? xs3[cq * 192 + ki * 64 + px] : 0.f;
            pr[cqi] = (bf16)v;
          }
          // group = k*4 + (cq>>3) = k*4 + (g2>>1); j = (g2&1)*4 + cqi
          *(bf16x4*)(valbuf + (k * 4 + (g2 >> 1)) * 512 + p * 8 + (g2 & 1) * 4) = pr;
        }
      }
      __syncthreads();
      if (w8) {
        __builtin_amdgcn_s_setprio(1);
#pragma unroll
        for (int ks = 0; ks < 9; ++ks) {
          bf16x8 a  = *(const bf16x8*)(wbase1 + cc * 288 + ks * 32);
          bf16x8 bv = *(const bf16x8*)(vb1 + ks * 2048);
          acc1 = __builtin_amdgcn_mfma_f32_16x16x32_bf16(a, bv, acc1, 0, 0, 0);
        }
        __builtin_amdgcn_s_setprio(0);
      }
    }
  }
  __syncthreads();
  if (w8) {
    int mf = wv & 1, nfq = wv >> 1;
    int so = mf * 16 + l4 * 4;
    int sp = nfq * 16 + l15;
#pragma unroll
    for (int r = 0; r < 4; ++r) S_lds[(so + r) * 64 + sp] = acc1[r];
  }
  __syncthreads();

  // ---- staging: wave wv stages 2 channels of half-chunk it2 (16 ch) ----
  auto stage = [&](int it2) {
    if (w8 && it2 < 8) {
      int ccs = it2 >> 1, g2s = it2 & 1;
      float* dstb = xslab + (it2 % 3) * BUFF;
#pragma unroll
      for (int u = 0; u < 2; ++u) {
        int chl = 2 * wv + u;                    // 0..15
        int ch  = ccs * 32 + g2s * 16 + chl;
        const float* srcb = xb + (size_t)ch * NPIX + l15 * 4;
        float* dst = dstb + chl * BUFC;
#pragma unroll
        for (int j = 0; j < 2; ++j) {
          int y = ho - 3 + j * 4 + l4;           // row-clamped staging:
          y = y < 0 ? 0 : (y > 63 ? 63 : y);     // slab row r holds clamp(ho-3+r)
          gl_lds16(srcb + y * 64, dst + j * 256);
        }
      }
    }
  };

  // prologue: 2-deep — batches 0 and 1 in flight; params compute overlaps
  stage(0);
  stage(1);
  __builtin_amdgcn_sched_barrier(0);

  // ---- sampling params: entry (k=wv, p=lane), one per thread ----
  float pw0, pw1, pw2, pw3;
  int   psa, psb, vg;
  {
    int k = wv, p = lane;
    float dy = S_lds[(2 * k) * 64 + p]     + off_b[2 * k];
    float dx = S_lds[(2 * k + 1) * 64 + p] + off_b[2 * k + 1];
    float mz = S_lds[(18 + k) * 64 + p]    + mask_b[k];
    float m  = 1.f / (1.f + expf(-mz));
    int ki = k / 3, kj = k % 3;
    float py = (float)(ho - 1 + ki) + dy;
    float px = (float)(p  - 1 + kj) + dx;
    float fy = floorf(py), fx = floorf(px);
    int y0 = (int)fy, x0 = (int)fx;
    float wy = py - fy, wx = px - fx;
    float vy0 = ((unsigned)y0       < 64u) ? 1.f : 0.f;
    float vy1 = ((unsigned)(y0 + 1) < 64u) ? 1.f : 0.f;
    float vx0 = ((unsigned)x0       < 64u) ? 1.f : 0.f;
    float vx1 = ((unsigned)(x0 + 1) < 64u) ? 1.f : 0.f;
    int r0  = y0 - (ho - 3);                    // slab-relative; clamped staging
    int ir0 = r0 < 0 ? 0 : (r0 > ROWS - 2 ? ROWS - 2 : r0);  // ir1 = ir0+1
    int c0  = x0 < 0 ? 0 : (x0 > 63 ? 63 : x0);
    int x1  = x0 + 1;
    int c1  = x1 < 0 ? 0 : (x1 > 63 ? 63 : x1);
    pw0 = (1.f - wy) * (1.f - wx) * m * vy0 * vx0;
    pw1 = (1.f - wy) * wx         * m * vy0 * vx1;
    pw2 = wy * (1.f - wx)         * m * vy1 * vx0;
    pw3 = wy * wx                 * m * vy1 * vx1;
    psa = ir0 * 64 + c0;      // corners (y0,x0)/(y0+1,x0) at +0,+64
    psb = ir0 * 64 + c1;      // corners (y0,x1)/(y0+1,x1) at +0,+64
    vg  = k * 4;              // valbuf group base for my tap
  }

  // ================= PHASE 2: 8 fat phases, counted vmcnt =================
  f32x4 acc[4] = {};
  bf16x8 aF[9] = {};
  const bf16* wbase = w_bf + (size_t)(wv * 16 + l15) * CK + l4 * 8;
  const bf16* vbase = valbuf + l4 * 512 + l15 * 8;   // + ks*2048 + nf*128

  // per-thread sampler for half-chunk g2 of the current buffer
  auto sample = [&](const float* sbuf, int g2s) {
#pragma unroll
    for (int h = 0; h < 2; ++h) {
      bf16x8 pack;
#pragma unroll
      for (int j = 0; j < 8; ++j) {
        const float* cb = sbuf + (h * 8 + j) * BUFC;
        float a0 = cb[psa], a1 = cb[psa + 64];   // ds_read2
        float b0 = cb[psb], b1 = cb[psb + 64];   // ds_read2
        pack[j] = (bf16)(pw0 * a0 + pw1 * b0 + pw2 * a1 + pw3 * b1);
      }
      *(bf16x8*)(valbuf + (vg + g2s * 2 + h) * 512 + lane * 8) = pack;
    }
  };

#pragma unroll 1
  for (int cc = 0; cc < 4; ++cc) {
    int it0 = 2 * cc;
    // ---- half-phase g2 = 0 ----
    asm volatile("s_waitcnt vmcnt(4)" ::: "memory");   // batch(it0) landed
    __builtin_amdgcn_s_barrier();
    __builtin_amdgcn_sched_barrier(0);
    if (w8) {                                          // A-frags -> registers
#pragma unroll
      for (int ks = 0; ks < 9; ++ks)
        aF[ks] = *(const bf16x8*)(wbase + cc * 288 + ks * 32);
    }
    __builtin_amdgcn_sched_barrier(0);                 // pin: aF before stage
    stage(it0 + 2);
    __builtin_amdgcn_sched_barrier(0);
    sample(xslab + (it0 % 3) * BUFF, 0);
    // ---- half-phase g2 = 1 ----
    if (cc < 3) asm volatile("s_waitcnt vmcnt(4)" ::: "memory");  // batch+aF
    else        asm volatile("s_waitcnt vmcnt(0)" ::: "memory");
    __builtin_amdgcn_s_barrier();
    __builtin_amdgcn_sched_barrier(0);
    stage(it0 + 3);
    __builtin_amdgcn_sched_barrier(0);
    sample(xslab + ((it0 + 1) % 3) * BUFF, 1);
    // ---- MFMA for this cc ----
    asm volatile("s_waitcnt lgkmcnt(0)" ::: "memory"); // my valbuf writes out
    __builtin_amdgcn_s_barrier();                      // everyone's out
    __builtin_amdgcn_sched_barrier(0);
    if (w8) {
      __builtin_amdgcn_s_setprio(1);
#pragma unroll
      for (int ks = 0; ks < 9; ++ks) {
#pragma unroll
        for (int nf = 0; nf < 4; ++nf) {
          bf16x8 bv = *(const bf16x8*)(vbase + ks * 2048 + nf * 128);
          acc[nf] = __builtin_amdgcn_mfma_f32_16x16x32_bf16(aF[ks], bv, acc[nf], 0, 0, 0);
        }
      }
      __builtin_amdgcn_s_setprio(0);
    }
  }

  // ---- epilogue: D row=(l4*4+r) (=o within wave), col=l15 (=px) ----
  if (w8) {
    float* ob = out + (size_t)b * O_ * NPIX + ho * 64;
#pragma unroll
    for (int nf = 0; nf < 4; ++nf)
#pragma unroll
      for (int r = 0; r < 4; ++r) {
        int o = wv * 16 + l4 * 4 + r;
        int p = nf * 16 + l15;
        ob[(size_t)o * NPIX + p] = acc[nf][r];
      }
  }
}

// ---------------- launch ----------------
extern "C" void kernel_launch(void* const* d_in, const int* in_sizes, int n_in,
                              void* d_out, int out_size, void* d_ws, size_t ws_size,
                              hipStream_t stream) {
  const float* x        = (const float*)d_in[0];
  const float* org_w    = (const float*)d_in[1];
  const float* offset_w = (const float*)d_in[2];
  const float* off_b    = (const float*)d_in[3];
  const float* mask_w   = (const float*)d_in[4];
  const float* mask_b   = (const float*)d_in[5];
  float* out = (float*)d_out;
  char*  ws  = (char*)d_ws;

  bf16* w_bf   = (bf16*)(ws + WS_WBF);
  bf16* wom_bf = (bf16*)(ws + WS_WOM);

  repack_kernel<<<720, 256, 0, stream>>>(org_w, offset_w, mask_w, w_bf, wom_bf);
  deform_fused_kernel<<<256, 576, 0, stream>>>(x, w_bf, wom_bf, off_b, mask_b, out);
}

// Round 11
// 45.934 us; speedup vs baseline: 1.6580x; 1.0337x over previous
//
#include <hip/hip_runtime.h>
#include <hip/hip_bf16.h>
#include <cmath>

#define B_    4
#define C_    128
#define O_    128
#define K2T   9
#define CK    1152          // C_*K2T
#define NPIX  4096          // 64*64
#define ROWS  8             // slab rows: clamp(ho-3 .. ho+4) (R8/R10-validated)
#define BUFC  512           // floats per channel slab (8 rows * 64)
#define BUFF  8192          // floats per buffer (16 ch * 512) = 32 KB
#define NGRP  36            // valbuf groups (kk>>3)

using bf16   = __bf16;
using bf16x8 = __attribute__((ext_vector_type(8))) __bf16;
using f32x4  = __attribute__((ext_vector_type(4))) float;

// ws layout (bytes):
//   [0, 294912)        w_bf   bf16[128*1152]  K-reordered: [o][cc*288 + k*32 + cq]
//   [294912, 368640)   wom_bf bf16[32*1152]   same K order, rows 27..31 zero
#define WS_WBF 0
#define WS_WOM 294912

// ---------------- kernel R: repack weights (K-reordered) ----------------
__global__ void __launch_bounds__(256) repack_kernel(
    const float* __restrict__ org_w, const float* __restrict__ offset_w,
    const float* __restrict__ mask_w, bf16* __restrict__ w_bf,
    bf16* __restrict__ wom_bf) {
  int t = blockIdx.x * 256 + threadIdx.x;   // 0 .. 160*1152-1
  if (t >= 160 * CK) return;
  int row = t / CK, r = t % CK;
  int cc = r / 288, rr = r % 288;
  int k = rr >> 5, cq = rr & 31;
  int c = cc * 32 + cq;
  if (row < 128) {
    w_bf[t] = (bf16)org_w[((size_t)row * C_ + c) * K2T + k];
  } else {
    int ch = row - 128;
    float v = 0.f;
    if (ch < 18)      v = offset_w[((size_t)ch * C_ + c) * K2T + k];
    else if (ch < 27) v = mask_w[((size_t)(ch - 18) * C_ + c) * K2T + k];
    wom_bf[(size_t)ch * CK + r] = (bf16)v;
  }
}

__device__ __forceinline__ void gl_lds16(const float* src, float* lds_uniform) {
  __builtin_amdgcn_global_load_lds(
      (const __attribute__((address_space(1))) void*)src,
      (__attribute__((address_space(3))) void*)lds_uniform, 16, 0, 0);
}

// ---- fused kernel: ONE unified 16-half-phase counted-vmcnt pipeline ----
// pass A (hp 0..7): offmask conv (zero-offset sampling). pass B (hp 8..15): deform.
__global__ void __launch_bounds__(576) deform_fused_kernel(
    const float* __restrict__ x, const bf16* __restrict__ w_bf,
    const bf16* __restrict__ wom_bf, const float* __restrict__ off_b,
    const float* __restrict__ mask_b, float* __restrict__ out) {
  __shared__ __align__(16) float xslab[3 * BUFF];        // 98,304 B (3 bufs)
  __shared__ __align__(16) bf16  valbuf[NGRP * 512];     // 36,864 B
  __shared__ __align__(16) float S_lds[32 * 64];         //  8,192 B

  int tid  = threadIdx.x;
  int bid0 = blockIdx.x;
  int bid  = (bid0 & 7) * 32 + (bid0 >> 3);  // XCD swizzle (bijective 256=8*32)
  int b    = bid >> 6, ho = bid & 63;
  int lane = tid & 63, wv = tid >> 6;        // 9 waves
  int l15  = lane & 15, l4 = lane >> 4;
  bool w8  = (wv < 8);

  const float* xb = x + (size_t)b * C_ * NPIX;

  // ---- staging: wave wv stages 2 channels of half-chunk it2 (16 ch) ----
  auto stage = [&](int it2) {
    if (w8 && it2 < 16) {
      int ccs = (it2 & 7) >> 1, g2s = it2 & 1;
      float* dstb = xslab + (it2 % 3) * BUFF;
#pragma unroll
      for (int u = 0; u < 2; ++u) {
        int chl = 2 * wv + u;                    // 0..15
        int ch  = ccs * 32 + g2s * 16 + chl;
        const float* srcb = xb + (size_t)ch * NPIX + l15 * 4;
        float* dst = dstb + chl * BUFC;
#pragma unroll
        for (int j = 0; j < 2; ++j) {
          int y = ho - 3 + j * 4 + l4;           // row-clamped staging:
          y = y < 0 ? 0 : (y > 63 ? 63 : y);     // slab row r holds clamp(ho-3+r)
          gl_lds16(srcb + y * 64, dst + j * 256);
        }
      }
    }
  };

  // ---- pass-A params (zero-offset im2col): tap k=wv at pixel p=lane ----
  float apw; int apsa;
  {
    int k = wv, p = lane;
    int ki = k / 3, kj = k % 3;
    int row = ho - 1 + ki, colu = p - 1 + kj;
    bool ok = ((unsigned)row < 64u) && ((unsigned)colu < 64u);
    int cc0 = colu < 0 ? 0 : (colu > 63 ? 63 : colu);
    apw  = ok ? 1.f : 0.f;
    apsa = (ki + 2) * 64 + cc0;   // slab row ki+2 holds clamp(ho-1+ki) exactly
  }

  // prologue: 2-deep prefetch
  stage(0);
  stage(1);
  __builtin_amdgcn_sched_barrier(0);

  // ---- per-pass state ----
  f32x4 acc1 = {};                 // pass A: S quadrant (mf=wv&1, nfq=wv>>1)
  f32x4 acc[4] = {};               // pass B: M-row wv*16, nf 0..3
  bf16x8 aF[9];
  float pw0 = 0.f, pw1 = 0.f, pw2 = 0.f, pw3 = 0.f;   // pass-B params (set at hp7)
  int   psa = 0, psb = 0;
  int   mf = wv & 1, nfq = wv >> 1;
  const bf16* wbase1 = wom_bf + (size_t)(mf * 16 + l15) * CK + l4 * 8;
  const bf16* wbase  = w_bf  + (size_t)(wv * 16 + l15) * CK + l4 * 8;
  const bf16* vb1    = valbuf + l4 * 512 + (nfq * 16 + l15) * 8;
  const bf16* vbase  = valbuf + l4 * 512 + l15 * 8;

#pragma unroll 1
  for (int hp = 0; hp < 16; ++hp) {
    int c2 = hp >> 1;
    bool passB = (c2 >= 4);
    int cc = c2 & 3;
    // counted wait: retire batch(hp) (+aF by odd hp); keep younger flying
    if (hp == 15) asm volatile("s_waitcnt vmcnt(0)" ::: "memory");
    else          asm volatile("s_waitcnt vmcnt(4)" ::: "memory");
    __builtin_amdgcn_s_barrier();            // all waves' batch(hp) landed
    __builtin_amdgcn_sched_barrier(0);
    if (!(hp & 1) && w8) {                   // A-frags for this cc -> registers
      const bf16* ab = (passB ? wbase : wbase1) + cc * 288;
#pragma unroll
      for (int ks = 0; ks < 9; ++ks) aF[ks] = *(const bf16x8*)(ab + ks * 32);
      __builtin_amdgcn_sched_barrier(0);     // pin: aF before stage
    }
    stage(hp + 2);
    __builtin_amdgcn_sched_barrier(0);
    // ---- sample 16 channels at my (k=wv, p=lane) -> 2 bf16x8 valbuf writes ----
    {
      const float* sbuf = xslab + (hp % 3) * BUFF;
      int grp = wv * 4 + (hp & 1) * 2;
      if (passB) {
#pragma unroll
        for (int h = 0; h < 2; ++h) {
          bf16x8 pack;
#pragma unroll
          for (int j = 0; j < 8; ++j) {
            const float* cb = sbuf + (h * 8 + j) * BUFC;
            float a0 = cb[psa], a1 = cb[psa + 64];   // ds_read2
            float b0 = cb[psb], b1 = cb[psb + 64];   // ds_read2
            pack[j] = (bf16)(pw0 * a0 + pw1 * b0 + pw2 * a1 + pw3 * b1);
          }
          *(bf16x8*)(valbuf + (grp + h) * 512 + lane * 8) = pack;
        }
      } else {
#pragma unroll
        for (int h = 0; h < 2; ++h) {
          bf16x8 pack;
#pragma unroll
          for (int j = 0; j < 8; ++j)
            pack[j] = (bf16)(apw * sbuf[(h * 8 + j) * BUFC + apsa]);
          *(bf16x8*)(valbuf + (grp + h) * 512 + lane * 8) = pack;
        }
      }
    }
    if (hp & 1) {
      asm volatile("s_waitcnt lgkmcnt(0)" ::: "memory");  // my valbuf writes out
      __builtin_amdgcn_s_barrier();                       // everyone's out
      __builtin_amdgcn_sched_barrier(0);
      if (w8) {
        __builtin_amdgcn_s_setprio(1);
        if (passB) {
#pragma unroll
          for (int ks = 0; ks < 9; ++ks) {
#pragma unroll
            for (int nf = 0; nf < 4; ++nf) {
              bf16x8 bv = *(const bf16x8*)(vbase + ks * 2048 + nf * 128);
              acc[nf] = __builtin_amdgcn_mfma_f32_16x16x32_bf16(aF[ks], bv, acc[nf], 0, 0, 0);
            }
          }
        } else {
#pragma unroll
          for (int ks = 0; ks < 9; ++ks) {
            bf16x8 bv = *(const bf16x8*)(vb1 + ks * 2048);
            acc1 = __builtin_amdgcn_mfma_f32_16x16x32_bf16(aF[ks], bv, acc1, 0, 0, 0);
          }
        }
        __builtin_amdgcn_s_setprio(0);
      }
    }
    if (hp == 7) {
      // ---- S ready: write S_lds, lgkm-only barrier (keep DMA flying), params ----
      if (w8) {
        int so = mf * 16 + l4 * 4;
        int sp = nfq * 16 + l15;
#pragma unroll
        for (int r = 0; r < 4; ++r) S_lds[(so + r) * 64 + sp] = acc1[r];
      }
      asm volatile("s_waitcnt lgkmcnt(0)" ::: "memory");
      __builtin_amdgcn_s_barrier();
      __builtin_amdgcn_sched_barrier(0);
      {
        int k = wv, p = lane;
        float dy = S_lds[(2 * k) * 64 + p]     + off_b[2 * k];
        float dx = S_lds[(2 * k + 1) * 64 + p] + off_b[2 * k + 1];
        float mz = S_lds[(18 + k) * 64 + p]    + mask_b[k];
        float m  = 1.f / (1.f + expf(-mz));
        int ki = k / 3, kj = k % 3;
        float py = (float)(ho - 1 + ki) + dy;
        float px = (float)(p  - 1 + kj) + dx;
        float fy = floorf(py), fx = floorf(px);
        int y0 = (int)fy, x0 = (int)fx;
        float wy = py - fy, wx = px - fx;
        float vy0 = ((unsigned)y0       < 64u) ? 1.f : 0.f;
        float vy1 = ((unsigned)(y0 + 1) < 64u) ? 1.f : 0.f;
        float vx0 = ((unsigned)x0       < 64u) ? 1.f : 0.f;
        float vx1 = ((unsigned)(x0 + 1) < 64u) ? 1.f : 0.f;
        int r0  = y0 - (ho - 3);
        int ir0 = r0 < 0 ? 0 : (r0 > ROWS - 2 ? ROWS - 2 : r0);  // ir1 = ir0+1
        int c0  = x0 < 0 ? 0 : (x0 > 63 ? 63 : x0);
        int x1  = x0 + 1;
        int c1  = x1 < 0 ? 0 : (x1 > 63 ? 63 : x1);
        pw0 = (1.f - wy) * (1.f - wx) * m * vy0 * vx0;
        pw1 = (1.f - wy) * wx         * m * vy0 * vx1;
        pw2 = wy * (1.f - wx)         * m * vy1 * vx0;
        pw3 = wy * wx                 * m * vy1 * vx1;
        psa = ir0 * 64 + c0;      // corners (y0,x0)/(y0+1,x0) at +0,+64
        psb = ir0 * 64 + c1;      // corners (y0,x1)/(y0+1,x1) at +0,+64
      }
    }
  }

  // ---- epilogue: D row=(l4*4+r) (=o within wave), col=l15 (=px) ----
  if (w8) {
    float* ob = out + (size_t)b * O_ * NPIX + ho * 64;
#pragma unroll
    for (int nf = 0; nf < 4; ++nf)
#pragma unroll
      for (int r = 0; r < 4; ++r) {
        int o = wv * 16 + l4 * 4 + r;
        int p = nf * 16 + l15;
        ob[(size_t)o * NPIX + p] = acc[nf][r];
      }
  }
}

// ---------------- launch ----------------
extern "C" void kernel_launch(void* const* d_in, const int* in_sizes, int n_in,
                              void* d_out, int out_size, void* d_ws, size_t ws_size,
                              hipStream_t stream) {
  const float* x        = (const float*)d_in[0];
  const float* org_w    = (const float*)d_in[1];
  const float* offset_w = (const float*)d_in[2];
  const float* off_b    = (const float*)d_in[3];
  const float* mask_w   = (const float*)d_in[4];
  const float* mask_b   = (const float*)d_in[5];
  float* out = (float*)d_out;
  char*  ws  = (char*)d_ws;

  bf16* w_bf   = (bf16*)(ws + WS_WBF);
  bf16* wom_bf = (bf16*)(ws + WS_WOM);

  repack_kernel<<<720, 256, 0, stream>>>(org_w, offset_w, mask_w, w_bf, wom_bf);
  deform_fused_kernel<<<256, 576, 0, stream>>>(x, w_bf, wom_bf, off_b, mask_b, out);
}